// Round 6
// baseline (78.037 us; speedup 1.0000x reference)
//
#include <hip/hip_runtime.h>

// ForexPrep: per row (T=8192): p = diff(x)/x[:-1]; scale = max|p| (row);
// pn = p/scale; ma = 7-window moving average; out[b,j] = {ma(j), x(j)}.
// x (4096, 8192) f32 -> out (4096, 8185, 2) f32.
//
// R5 = R4 (register rolling window + LDS transpose + nontemporal dense
// stores) + persistent blocks (2/CU) grid-striding 8 rows each, with the
// NEXT row's global loads issued before the current row's reduce+store
// phase so the read and write streams stay concurrently in flight.

constexpr int T_LEN = 8192;
constexpr int GAP_  = 7;
constexpr int OUTW  = T_LEN - GAP_;     // 8185
constexpr int NP    = T_LEN - 1;        // 8191
constexpr int NTHR  = 512;
constexpr int CH    = 16;               // outputs per thread
constexpr int ROWF  = OUTW * 2;         // 16370 floats per output row
constexpr int SEGF  = 8192;             // floats per segment
constexpr int NBLK  = 512;              // persistent grid: 2 blocks/CU

typedef float v2f __attribute__((ext_vector_type(2)));

#define LOAD_ROW(xr, dst)                                                    \
    {                                                                        \
        _Pragma("unroll")                                                    \
        for (int q = 0; q < 6; ++q) {                                        \
            const int e = base + 4 * q;                                      \
            if (e + 3 < T_LEN) {                                             \
                const float4 v = *reinterpret_cast<const float4*>((xr) + e); \
                dst[4*q+0] = v.x; dst[4*q+1] = v.y;                          \
                dst[4*q+2] = v.z; dst[4*q+3] = v.w;                          \
            } else {                                                         \
                _Pragma("unroll")                                            \
                for (int e2 = 0; e2 < 4; ++e2)                               \
                    dst[4*q+e2] = (e + e2 < T_LEN) ? (xr)[e + e2] : 1.0f;    \
            }                                                                \
        }                                                                    \
    }

__global__ __launch_bounds__(NTHR, 4)   // 4 waves/EU -> 2 blocks/CU, VGPR<=128
void forex_prep_kernel(const float* __restrict__ x, float* __restrict__ out,
                       int n_rows) {
    const int t    = threadIdx.x;
    const int base = CH * t;

    __shared__ float tile[256 * 33];    // 33 KB transpose tile (pad-1 per 32)
    __shared__ float red[NTHR / 64];

    int row = blockIdx.x;
    if (row >= n_rows) return;
    const int stride = gridDim.x;

    float xv [CH + GAP_ + 1];           // 24: current row
    float nxv[CH + GAP_ + 1];           // 24: prefetched next row
    LOAD_ROW(x + (size_t)row * T_LEN, xv);

    for (; row < n_rows; row += stride) {
        const int nrow = row + stride;

        // ---- p[k] = x[base+k+1]/x[base+k] - 1, zeroed where invalid.
        float p[CH + GAP_ - 1];         // 22
#pragma unroll
        for (int k = 0; k < CH + GAP_ - 1; ++k) {
            const float pk = fmaf(xv[k + 1], __builtin_amdgcn_rcpf(xv[k]), -1.0f);
            p[k] = (base + k < NP) ? pk : 0.0f;
        }
        float m = 0.0f;
#pragma unroll
        for (int k = 0; k < CH; ++k) m = fmaxf(m, fabsf(p[k]));

        // ---- Prefetch next row NOW: latency hides under reduce + stores.
        if (nrow < n_rows) {
            const float* xrn = x + (size_t)nrow * T_LEN;
            LOAD_ROW(xrn, nxv);
        }

        // ---- Block max reduce.
#pragma unroll
        for (int off = 32; off > 0; off >>= 1)
            m = fmaxf(m, __shfl_xor(m, off, 64));
        if ((t & 63) == 0) red[t >> 6] = m;
        __syncthreads();
        float scale = red[0];
#pragma unroll
        for (int wv = 1; wv < NTHR / 64; ++wv) scale = fmaxf(scale, red[wv]);
        const float inv = __builtin_amdgcn_rcpf(scale * (float)GAP_);

        // ---- Rolling 7-window sums -> ma in registers.
        float ma[CH];
        float w = ((p[0] + p[1]) + (p[2] + p[3])) + ((p[4] + p[5]) + p[6]);
        ma[0] = w * inv;
#pragma unroll
        for (int k = 1; k < CH; ++k) {
            w += p[k + GAP_ - 1] - p[k - 1];
            ma[k] = w * inv;
        }

        // ---- Two segments: transpose through LDS, dense NT float2 stores.
        const int my_seg = t >> 8;
        const int u = t & 255;
        float* __restrict__ orow = out + (size_t)row * ROWF;

#pragma unroll
        for (int seg = 0; seg < 2; ++seg) {
            if (my_seg == seg) {
                float* tb = tile + 33 * u;   // conflict-free pad-33
#pragma unroll
                for (int k = 0; k < CH; ++k) {
                    tb[2*k]     = ma[k];
                    tb[2*k + 1] = xv[k];
                }
            }
            __syncthreads();                 // tile ready
            const int nf = (seg == 0) ? SEGF : (ROWF - SEGF);  // 8192 / 8178
            float* __restrict__ gb = orow + seg * SEGF;
#pragma unroll
            for (int q = 0; q < 8; ++q) {
                const int L = (q * NTHR + t) * 2;   // dense even offsets
                if (L < nf) {
                    const int Lp = L + (L >> 5);    // pad-1 per 32 floats
                    const v2f val = {tile[Lp], tile[Lp + 1]};
                    __builtin_nontemporal_store(val,
                        reinterpret_cast<v2f*>(gb + L));
                }
            }
            __syncthreads();                 // tile safe to rewrite
        }

        // ---- Rotate prefetched row into place.
        if (nrow < n_rows) {
#pragma unroll
            for (int e = 0; e < CH + GAP_ + 1; ++e) xv[e] = nxv[e];
        }
    }
}

extern "C" void kernel_launch(void* const* d_in, const int* in_sizes, int n_in,
                              void* d_out, int out_size, void* d_ws, size_t ws_size,
                              hipStream_t stream) {
    const float* x = (const float*)d_in[0];
    float* out = (float*)d_out;
    const int n_rows = in_sizes[0] / T_LEN;   // 4096
    const int grid = (n_rows < NBLK) ? n_rows : NBLK;
    hipLaunchKernelGGL(forex_prep_kernel, dim3(grid), dim3(NTHR), 0, stream,
                       x, out, n_rows);
}

// Round 7
// 67.887 us; speedup vs baseline: 1.1495x; 1.1495x over previous
//
#include <hip/hip_runtime.h>

// ForexPrep: per row (T=8192): p = diff(x)/x[:-1]; scale = max|p| (row);
// pn = p/scale; ma = 7-window moving average; out[b,j] = {ma(j), x(j)}.
// x (4096, 8192) f32 -> out (4096, 8185, 2) f32.
//
// R6 = R4 (register rolling window + LDS transpose + nontemporal stores)
// with FLOAT4 output stores (1 KB/wave-instruction, copy-kernel density).
// Row byte base ≡ 8*(row&1) mod 16, so odd rows shift the float4 grouping
// by 2 floats with float2 edge patches (block-uniform; no divergence).

constexpr int T_LEN = 8192;
constexpr int GAP_  = 7;
constexpr int OUTW  = T_LEN - GAP_;     // 8185
constexpr int NP    = T_LEN - 1;        // 8191
constexpr int NTHR  = 512;
constexpr int CH    = 16;               // outputs per thread
constexpr int ROWF  = OUTW * 2;         // 16370 floats per output row
constexpr int SEGF  = 8192;             // floats per tile segment

typedef float v2f __attribute__((ext_vector_type(2)));
typedef float v4f __attribute__((ext_vector_type(4)));

__global__ __launch_bounds__(NTHR)
void forex_prep_kernel(const float* __restrict__ x, float* __restrict__ out,
                       int n_rows) {
    const int row = blockIdx.x;
    if (row >= n_rows) return;
    const int t = threadIdx.x;

    __shared__ float tile[256 * 33];    // 33 KB transpose tile (pad-1 per 32)
    __shared__ float red[NTHR / 64];

    const float* __restrict__ xr = x + (size_t)row * T_LEN;
    const int base = CH * t;

    // ---- Load x[base .. base+23] into registers (6x float4; OOB -> 1.0f).
    float xv[CH + GAP_ + 1];
#pragma unroll
    for (int q = 0; q < 6; ++q) {
        const int e = base + 4 * q;
        if (e + 3 < T_LEN) {
            const float4 v = *reinterpret_cast<const float4*>(xr + e);
            xv[4*q+0] = v.x; xv[4*q+1] = v.y; xv[4*q+2] = v.z; xv[4*q+3] = v.w;
        } else {
#pragma unroll
            for (int e2 = 0; e2 < 4; ++e2)
                xv[4*q+e2] = (e + e2 < T_LEN) ? xr[e + e2] : 1.0f;
        }
    }

    // ---- p[k] = x[base+k+1]/x[base+k] - 1, zeroed where invalid.
    float p[CH + GAP_ - 1];             // 22
#pragma unroll
    for (int k = 0; k < CH + GAP_ - 1; ++k) {
        const float pk = fmaf(xv[k + 1], __builtin_amdgcn_rcpf(xv[k]), -1.0f);
        p[k] = (base + k < NP) ? pk : 0.0f;
    }

    // ---- Block max of |p| over own share, then block reduce.
    float m = 0.0f;
#pragma unroll
    for (int k = 0; k < CH; ++k) m = fmaxf(m, fabsf(p[k]));
#pragma unroll
    for (int off = 32; off > 0; off >>= 1)
        m = fmaxf(m, __shfl_xor(m, off, 64));
    if ((t & 63) == 0) red[t >> 6] = m;
    __syncthreads();
    float scale = red[0];
#pragma unroll
    for (int wv = 1; wv < NTHR / 64; ++wv) scale = fmaxf(scale, red[wv]);
    const float inv = __builtin_amdgcn_rcpf(scale * (float)GAP_);  // 1/(7*scale)

    // ---- Rolling 7-window sums -> ma[0..15] in registers.
    float ma[CH];
    float w = ((p[0] + p[1]) + (p[2] + p[3])) + ((p[4] + p[5]) + p[6]);
    ma[0] = w * inv;
#pragma unroll
    for (int k = 1; k < CH; ++k) {
        w += p[k + GAP_ - 1] - p[k - 1];
        ma[k] = w * inv;
    }

    // ---- Two segments: transpose through LDS, then dense NT float4 stores.
    const int s = row & 1;              // alignment shift
    const int my_seg = t >> 8;          // threads 0..255 own outputs [0,4096)
    const int u = t & 255;
    float* __restrict__ orow = out + (size_t)row * ROWF;

#pragma unroll
    for (int seg = 0; seg < 2; ++seg) {
        if (my_seg == seg) {
            float* tb = tile + 33 * u;  // conflict-free pad-33
#pragma unroll
            for (int k = 0; k < CH; ++k) {
                tb[2*k]     = ma[k];
                tb[2*k + 1] = xv[k];
            }
        }
        __syncthreads();                // tile ready

        // tile[Lr + (Lr>>5)] == output float (seg*SEGF + Lr) of this row
        #define TT(Lr) tile[(Lr) + ((Lr) >> 5)]

        if (s == 0) {
            const int nf4 = (seg == 0) ? 2048 : 2044;
#pragma unroll
            for (int q = 0; q < 4; ++q) {
                const int f = q * NTHR + t;
                if (f < nf4) {
                    const int Lr = 4 * f;
                    const v4f val = {TT(Lr), TT(Lr+1), TT(Lr+2), TT(Lr+3)};
                    __builtin_nontemporal_store(val,
                        reinterpret_cast<v4f*>(orow + seg * SEGF + Lr));
                }
            }
            if (seg == 1 && t == 0) {   // trailing float2: floats 16368,16369
                const v2f val = {TT(8176), TT(8177)};
                __builtin_nontemporal_store(val,
                    reinterpret_cast<v2f*>(orow + SEGF + 8176));
            }
        } else {
            const int nf4 = (seg == 0) ? 2047 : 2044;
#pragma unroll
            for (int q = 0; q < 4; ++q) {
                const int f = q * NTHR + t;
                if (f < nf4) {
                    const int Lr = 2 + 4 * f;
                    const v4f val = {TT(Lr), TT(Lr+1), TT(Lr+2), TT(Lr+3)};
                    __builtin_nontemporal_store(val,
                        reinterpret_cast<v4f*>(orow + seg * SEGF + Lr));
                }
            }
            if (t == 0) {               // leading float2 of this segment
                const v2f val = {TT(0), TT(1)};
                __builtin_nontemporal_store(val,
                    reinterpret_cast<v2f*>(orow + seg * SEGF));
            }
            if (seg == 0 && t == 1) {   // floats 8190,8191
                const v2f val = {TT(8190), TT(8191)};
                __builtin_nontemporal_store(val,
                    reinterpret_cast<v2f*>(orow + 8190));
            }
        }
        #undef TT

        if (seg == 0) __syncthreads();  // copy done before seg-1 overwrite
    }
}

extern "C" void kernel_launch(void* const* d_in, const int* in_sizes, int n_in,
                              void* d_out, int out_size, void* d_ws, size_t ws_size,
                              hipStream_t stream) {
    const float* x = (const float*)d_in[0];
    float* out = (float*)d_out;
    const int n_rows = in_sizes[0] / T_LEN;   // 4096
    dim3 grid(n_rows), block(NTHR);
    hipLaunchKernelGGL(forex_prep_kernel, grid, block, 0, stream, x, out, n_rows);
}